// Round 3
// baseline (274.814 us; speedup 1.0000x reference)
//
#include <hip/hip_runtime.h>
#include <math.h>

#define NM 131072
#define PP 256
#define BB 32

#define CHUNKS 512
#define CHUNK_SZ 256   // NM / CHUNKS

#define INF_F 3.0e38f

// Branchless sorted insert into (d0<=d1<=d2) top-3 list.
// Strict < : on exact ties the incumbent (earlier-scanned = lower index) wins,
// matching lax.top_k stable tie-break.
__device__ __forceinline__ void ins3(float d, int i,
    float& d0, float& d1, float& d2, int& i0, int& i1, int& i2) {
  bool l0 = d < d0, l1 = d < d1, l2 = d < d2;
  d2 = l1 ? d1 : (l2 ? d : d2);
  i2 = l1 ? i1 : (l2 ? i : i2);
  d1 = l0 ? d0 : (l1 ? d : d1);
  i1 = l0 ? i0 : (l1 ? i : i1);
  d0 = l0 ? d : d0;
  i0 = l0 ? i : i0;
}

// Exact-fp32 distance matching the reference's (a-b)^2 + (c-d)^2 (no fma contraction).
__device__ __forceinline__ float dist2(float ax, float ay, float bx, float by) {
  float dx = ax - bx, dy = ay - by;
  return __fadd_rn(__fmul_rn(dx, dx), __fmul_rn(dy, dy));
}

// ---------- KNN A stage 1: 4 independent insert chains per thread (ILP) ----------
// Block = mesh chunk, thread = pivotal point. Chain j scans indices
// [base+64j, base+64j+64) in ascending order; chains merged in range order,
// so tie semantics match a single ascending scan.
__global__ void knnA_partial(const float* __restrict__ mesh, const float* __restrict__ piv,
                             float* __restrict__ candd, int* __restrict__ candi) {
  const int p = threadIdx.x;
  const int c = blockIdx.x;
  const float px = piv[2 * p], py = piv[2 * p + 1];
  float D0[4], D1[4], D2[4];
  int I0[4], I1[4], I2[4];
#pragma unroll
  for (int j = 0; j < 4; ++j) { D0[j] = D1[j] = D2[j] = INF_F; I0[j] = I1[j] = I2[j] = 0; }
  const int base = c * CHUNK_SZ;
#pragma unroll 2
  for (int i = 0; i < CHUNK_SZ / 4; ++i) {
#pragma unroll
    for (int j = 0; j < 4; ++j) {
      int idx = base + j * (CHUNK_SZ / 4) + i;
      float mx = mesh[2 * idx];      // wave-uniform -> scalar load
      float my = mesh[2 * idx + 1];
      ins3(dist2(px, py, mx, my), idx, D0[j], D1[j], D2[j], I0[j], I1[j], I2[j]);
    }
  }
  float d0 = D0[0], d1 = D1[0], d2 = D2[0];
  int i0 = I0[0], i1 = I1[0], i2 = I2[0];
#pragma unroll
  for (int j = 1; j < 4; ++j) {
    ins3(D0[j], I0[j], d0, d1, d2, i0, i1, i2);
    ins3(D1[j], I1[j], d0, d1, d2, i0, i1, i2);
    ins3(D2[j], I2[j], d0, d1, d2, i0, i1, i2);
  }
  // transposed layout [p][c] so the merge kernel reads coalesced
  int o = (p * CHUNKS + c) * 3;
  candd[o] = d0; candd[o + 1] = d1; candd[o + 2] = d2;
  candi[o] = i0; candi[o + 1] = i1; candi[o + 2] = i2;
}

// Stage 2: block = pivotal point; thread t merges chunks 2t,2t+1 (coalesced reads).
__global__ void knnA_merge(const float* __restrict__ candd, const int* __restrict__ candi,
                           float* __restrict__ wA, int* __restrict__ idxA) {
  const int p = blockIdx.x;
  const int t = threadIdx.x;
  __shared__ float sd[PP * 3];
  __shared__ int si[PP * 3];
  __shared__ float sd2[32 * 3];
  __shared__ int si2[32 * 3];

  float d0 = INF_F, d1 = INF_F, d2 = INF_F;
  int i0 = 0, i1 = 0, i2 = 0;
#pragma unroll
  for (int cc = 0; cc < 2; ++cc) {
    int o = (p * CHUNKS + 2 * t + cc) * 3;
#pragma unroll
    for (int k = 0; k < 3; ++k) ins3(candd[o + k], candi[o + k], d0, d1, d2, i0, i1, i2);
  }
  sd[t * 3] = d0; sd[t * 3 + 1] = d1; sd[t * 3 + 2] = d2;
  si[t * 3] = i0; si[t * 3 + 1] = i1; si[t * 3 + 2] = i2;
  __syncthreads();
  if (t < 32) {
    d0 = d1 = d2 = INF_F; i0 = i1 = i2 = 0;
    for (int j = t * 8; j < t * 8 + 8; ++j)
      for (int k = 0; k < 3; ++k) ins3(sd[j * 3 + k], si[j * 3 + k], d0, d1, d2, i0, i1, i2);
    sd2[t * 3] = d0; sd2[t * 3 + 1] = d1; sd2[t * 3 + 2] = d2;
    si2[t * 3] = i0; si2[t * 3 + 1] = i1; si2[t * 3 + 2] = i2;
  }
  __syncthreads();
  if (t == 0) {
    d0 = d1 = d2 = INF_F; i0 = i1 = i2 = 0;
    for (int j = 0; j < 32; ++j)
      for (int k = 0; k < 3; ++k) ins3(sd2[j * 3 + k], si2[j * 3 + k], d0, d1, d2, i0, i1, i2);
    wA[p * 3 + 0] = 1.0f / fmaxf(d0, 1e-16f); idxA[p * 3 + 0] = i0;
    wA[p * 3 + 1] = 1.0f / fmaxf(d1, 1e-16f); idxA[p * 3 + 1] = i1;
    wA[p * 3 + 2] = 1.0f / fmaxf(d2, 1e-16f); idxA[p * 3 + 2] = i2;
  }
}

// ---------- Gather + LayerNorm + weighted interp -> y[B,256,3] ----------
__global__ void gather_ln(const float* __restrict__ node, const float* __restrict__ wA,
                          const int* __restrict__ idxA, const float* __restrict__ gamma,
                          const float* __restrict__ beta, float* __restrict__ y) {
  const int b = blockIdx.x >> 2;
  const int p = ((blockIdx.x & 3) << 6) + threadIdx.x;
  const float g0 = gamma[0], g1 = gamma[1], g2 = gamma[2];
  const float be0 = beta[0], be1 = beta[1], be2 = beta[2];
  float num0 = 0.f, num1 = 0.f, num2 = 0.f, den = 0.f;
#pragma unroll
  for (int k = 0; k < 3; ++k) {
    int idx = idxA[p * 3 + k];
    float w = wA[p * 3 + k];
    const float* r = node + ((size_t)b * NM + idx) * 3;
    float a0 = r[0], a1 = r[1], a2 = r[2];
    float mu = (a0 + a1 + a2) * (1.0f / 3.0f);
    float e0 = a0 - mu, e1 = a1 - mu, e2 = a2 - mu;
    float var = (e0 * e0 + e1 * e1 + e2 * e2) * (1.0f / 3.0f);
    float sc = 1.0f / sqrtf(var + 1e-5f);
    float v0 = e0 * sc * g0 + be0, v1 = e1 * sc * g1 + be1, v2 = e2 * sc * g2 + be2;
    num0 += v0 * w; num1 += v1 * w; num2 += v2 * w; den += w;
  }
  int o = (b * PP + p) * 3;
  y[o] = num0 / den; y[o + 1] = num1 / den; y[o + 2] = num2 / den;
}

// ---------- q/Q/K projection; output head-major Qh/Kh [b][h][q][16] ----------
__global__ void qqk_kernel(const float* __restrict__ y, const float* __restrict__ piv,
                           const float* __restrict__ Wf, const float* __restrict__ bf,
                           const float* __restrict__ Wp, const float* __restrict__ bp,
                           const float* __restrict__ ipw, const float* __restrict__ ipb,
                           float* __restrict__ Qh, float* __restrict__ Kh) {
  const int b = blockIdx.x >> 5;
  const int ptile = (blockIdx.x & 31) * 8;
  const int t = threadIdx.x;
  const int e = t & 63;
  const int half = t >> 6;  // 0 -> Q, 1 -> K
  __shared__ float qs[8][64];

  {
    float wf0 = Wf[e * 3], wf1 = Wf[e * 3 + 1], wf2 = Wf[e * 3 + 2];
    float wp0 = Wp[e * 2], wp1 = Wp[e * 2 + 1];
    float cst = bf[e] + bp[e];
    for (int r = half; r < 8; r += 2) {
      int p = ptile + r;
      const float* yr = y + (b * PP + p) * 3;
      float pe = piv[2 * p] * wp0 + piv[2 * p + 1] * wp1;
      qs[r][e] = yr[0] * wf0 + yr[1] * wf1 + yr[2] * wf2 + cst + pe;
    }
  }
  __syncthreads();

  const int row = half * 64 + e;
  float wreg[64];
  const float4* W4 = (const float4*)(ipw + row * 64);
#pragma unroll
  for (int j = 0; j < 16; ++j) {
    float4 v = W4[j];
    wreg[4 * j] = v.x; wreg[4 * j + 1] = v.y; wreg[4 * j + 2] = v.z; wreg[4 * j + 3] = v.w;
  }
  float bias = ipb[row];
  float* dst = half ? Kh : Qh;
  const int h = e >> 4, d = e & 15;
#pragma unroll 2
  for (int r = 0; r < 8; ++r) {
    float acc = bias;
#pragma unroll
    for (int j = 0; j < 64; ++j) acc += qs[r][j] * wreg[j];
    int p = ptile + r;
    dst[(((b * 4 + h) * PP) + p) * 16 + d] = acc;
  }
}

// ---------- attention: block = (b, h, q-half); thread = q-row; online softmax ----------
__global__ void attn_kernel(const float* __restrict__ Qh, const float* __restrict__ Kh,
                            const float* __restrict__ y, float* __restrict__ y2) {
  const int b = blockIdx.x >> 3;
  const int h = (blockIdx.x >> 1) & 3;
  const int qh = blockIdx.x & 1;
  const int t = threadIdx.x;          // 128 threads
  const int q = qh * 128 + t;

  __shared__ float Ks[PP * 16];       // 16 KB, head h's K
  __shared__ float ys[PP * 3];        // 3 KB

  {
    const float4* src = (const float4*)(Kh + (size_t)(b * 4 + h) * PP * 16);
    float4* dst = (float4*)Ks;
#pragma unroll
    for (int j = 0; j < 8; ++j) dst[j * 128 + t] = src[j * 128 + t];
    const float* ysrc = y + b * PP * 3;
#pragma unroll
    for (int j = 0; j < 6; ++j) ys[j * 128 + t] = ysrc[j * 128 + t];
  }
  __syncthreads();

  const float4* q4 = (const float4*)(Qh + ((size_t)((b * 4 + h) * PP) + q) * 16);
  float4 qa = q4[0], qb = q4[1], qc = q4[2], qd = q4[3];

  float m = -INF_F, l = 0.f, a0 = 0.f, a1 = 0.f, a2 = 0.f;
#pragma unroll 4
  for (int k = 0; k < PP; ++k) {
    const float4* kr = (const float4*)(Ks + k * 16);   // broadcast read
    float4 k0 = kr[0], k1 = kr[1], k2 = kr[2], k3 = kr[3];
    float dot = qa.x * k0.x + qa.y * k0.y + qa.z * k0.z + qa.w * k0.w
              + qb.x * k1.x + qb.y * k1.y + qb.z * k1.z + qb.w * k1.w
              + qc.x * k2.x + qc.y * k2.y + qc.z * k2.z + qc.w * k2.w
              + qd.x * k3.x + qd.y * k3.y + qd.z * k3.z + qd.w * k3.w;
    float s = dot * 0.25f;            // 1/sqrt(DH=16)
    float mn = fmaxf(m, s);
    float p = __expf(s - mn);
    float sc = __expf(m - mn);
    float y0 = ys[k * 3], y1 = ys[k * 3 + 1], yy2 = ys[k * 3 + 2];
    l = l * sc + p;
    a0 = a0 * sc + p * y0;
    a1 = a1 * sc + p * y1;
    a2 = a2 * sc + p * yy2;
    m = mn;
  }
  float inv = 0.25f / l;              // mean over 4 heads
  float* o = y2 + (b * PP + q) * 3;
  atomicAdd(o + 0, a0 * inv);
  atomicAdd(o + 1, a1 * inv);
  atomicAdd(o + 2, a2 * inv);
}

// ---------- KNN B + output: 4 insert chains per thread, nt stores ----------
__global__ void knnB_out(const float* __restrict__ mesh, const float* __restrict__ piv,
                         const float* __restrict__ y2, float* __restrict__ out) {
  const int m = blockIdx.x * blockDim.x + threadIdx.x;
  const float mx = mesh[2 * m], my = mesh[2 * m + 1];
  float D0[4], D1[4], D2[4];
  int I0[4], I1[4], I2[4];
#pragma unroll
  for (int j = 0; j < 4; ++j) { D0[j] = D1[j] = D2[j] = INF_F; I0[j] = I1[j] = I2[j] = 0; }
#pragma unroll 2
  for (int i = 0; i < PP / 4; ++i) {
#pragma unroll
    for (int j = 0; j < 4; ++j) {
      int idx = j * (PP / 4) + i;
      float px = piv[2 * idx], py = piv[2 * idx + 1];  // wave-uniform -> scalar loads
      ins3(dist2(mx, my, px, py), idx, D0[j], D1[j], D2[j], I0[j], I1[j], I2[j]);
    }
  }
  float d0 = D0[0], d1 = D1[0], d2 = D2[0];
  int i0 = I0[0], i1 = I1[0], i2 = I2[0];
#pragma unroll
  for (int j = 1; j < 4; ++j) {
    ins3(D0[j], I0[j], d0, d1, d2, i0, i1, i2);
    ins3(D1[j], I1[j], d0, d1, d2, i0, i1, i2);
    ins3(D2[j], I2[j], d0, d1, d2, i0, i1, i2);
  }
  float w0 = 1.0f / fmaxf(d0, 1e-16f);
  float w1 = 1.0f / fmaxf(d1, 1e-16f);
  float w2 = 1.0f / fmaxf(d2, 1e-16f);
  float inv = 1.0f / (w0 + w1 + w2);
  int o0 = i0 * 3, o1 = i1 * 3, o2 = i2 * 3;
#pragma unroll 4
  for (int b = 0; b < BB; ++b) {
    const float* yb = y2 + b * PP * 3;
    float n0 = (w0 * yb[o0] + w1 * yb[o1] + w2 * yb[o2]) * inv;
    float n1 = (w0 * yb[o0 + 1] + w1 * yb[o1 + 1] + w2 * yb[o2 + 1]) * inv;
    float n2 = (w0 * yb[o0 + 2] + w1 * yb[o1 + 2] + w2 * yb[o2 + 2]) * inv;
    float* op = out + ((size_t)b * NM + m) * 3;
    __builtin_nontemporal_store(n0, op + 0);
    __builtin_nontemporal_store(n1, op + 1);
    __builtin_nontemporal_store(n2, op + 2);
  }
}

extern "C" void kernel_launch(void* const* d_in, const int* in_sizes, int n_in,
                              void* d_out, int out_size, void* d_ws, size_t ws_size,
                              hipStream_t stream) {
  const float* node  = (const float*)d_in[0];
  const float* mesh  = (const float*)d_in[1];
  const float* piv   = (const float*)d_in[2];
  const float* gamma = (const float*)d_in[3];
  const float* beta  = (const float*)d_in[4];
  const float* Wf    = (const float*)d_in[5];
  const float* bf    = (const float*)d_in[6];
  const float* Wp    = (const float*)d_in[7];
  const float* bp    = (const float*)d_in[8];
  const float* ipw   = (const float*)d_in[9];
  const float* ipb   = (const float*)d_in[10];
  float* out = (float*)d_out;

  // workspace layout (floats)
  float* candd = (float*)d_ws;                     // PP*CHUNKS*3 (transposed [p][c])
  int*   candi = (int*)(candd + CHUNKS * PP * 3);  // PP*CHUNKS*3
  float* wA    = (float*)(candi + CHUNKS * PP * 3);// PP*3
  int*   idxA  = (int*)(wA + PP * 3);              // PP*3
  float* y     = (float*)(idxA + PP * 3);          // BB*PP*3
  float* Qh    = y + BB * PP * 3;                  // BB*4*PP*16
  float* Kh    = Qh + BB * PP * 64;                // BB*4*PP*16
  float* y2    = Kh + BB * PP * 64;                // BB*PP*3

  hipMemsetAsync(y2, 0, BB * PP * 3 * sizeof(float), stream);

  knnA_partial<<<CHUNKS, PP, 0, stream>>>(mesh, piv, candd, candi);
  knnA_merge<<<PP, 256, 0, stream>>>(candd, candi, wA, idxA);
  gather_ln<<<BB * 4, 64, 0, stream>>>(node, wA, idxA, gamma, beta, y);
  qqk_kernel<<<BB * 32, 128, 0, stream>>>(y, piv, Wf, bf, Wp, bp, ipw, ipb, Qh, Kh);
  attn_kernel<<<BB * 4 * 2, 128, 0, stream>>>(Qh, Kh, y, y2);
  knnB_out<<<NM / 256, 256, 0, stream>>>(mesh, piv, y2, out);
}

// Round 4
// 231.732 us; speedup vs baseline: 1.1859x; 1.1859x over previous
//
#include <hip/hip_runtime.h>
#include <math.h>

#define NM 131072
#define PP 256
#define BB 32

#define CHUNKS 512
#define CHUNK_SZ 256   // NM / CHUNKS

#define INF_F 3.0e38f

// Branchless sorted insert into (d0<=d1<=d2) top-3 list.
// Strict < : on exact ties the incumbent (earlier-scanned = lower index) wins,
// matching lax.top_k stable tie-break.
__device__ __forceinline__ void ins3(float d, int i,
    float& d0, float& d1, float& d2, int& i0, int& i1, int& i2) {
  bool l0 = d < d0, l1 = d < d1, l2 = d < d2;
  d2 = l1 ? d1 : (l2 ? d : d2);
  i2 = l1 ? i1 : (l2 ? i : i2);
  d1 = l0 ? d0 : (l1 ? d : d1);
  i1 = l0 ? i0 : (l1 ? i : i1);
  d0 = l0 ? d : d0;
  i0 = l0 ? i : i0;
}

// Exact-fp32 distance matching the reference's (a-b)^2 + (c-d)^2 (no fma contraction).
__device__ __forceinline__ float dist2(float ax, float ay, float bx, float by) {
  float dx = ax - bx, dy = ay - by;
  return __fadd_rn(__fmul_rn(dx, dx), __fmul_rn(dy, dy));
}

// ---------- KNN A stage 1: 4 independent insert chains per thread (ILP) ----------
__global__ void knnA_partial(const float* __restrict__ mesh, const float* __restrict__ piv,
                             float* __restrict__ candd, int* __restrict__ candi) {
  const int p = threadIdx.x;
  const int c = blockIdx.x;
  const float px = piv[2 * p], py = piv[2 * p + 1];
  float D0[4], D1[4], D2[4];
  int I0[4], I1[4], I2[4];
#pragma unroll
  for (int j = 0; j < 4; ++j) { D0[j] = D1[j] = D2[j] = INF_F; I0[j] = I1[j] = I2[j] = 0; }
  const int base = c * CHUNK_SZ;
#pragma unroll 2
  for (int i = 0; i < CHUNK_SZ / 4; ++i) {
#pragma unroll
    for (int j = 0; j < 4; ++j) {
      int idx = base + j * (CHUNK_SZ / 4) + i;
      float mx = mesh[2 * idx];      // wave-uniform -> scalar load
      float my = mesh[2 * idx + 1];
      ins3(dist2(px, py, mx, my), idx, D0[j], D1[j], D2[j], I0[j], I1[j], I2[j]);
    }
  }
  float d0 = D0[0], d1 = D1[0], d2 = D2[0];
  int i0 = I0[0], i1 = I1[0], i2 = I2[0];
#pragma unroll
  for (int j = 1; j < 4; ++j) {
    ins3(D0[j], I0[j], d0, d1, d2, i0, i1, i2);
    ins3(D1[j], I1[j], d0, d1, d2, i0, i1, i2);
    ins3(D2[j], I2[j], d0, d1, d2, i0, i1, i2);
  }
  // transposed layout [p][c] so the merge kernel reads coalesced
  int o = (p * CHUNKS + c) * 3;
  candd[o] = d0; candd[o + 1] = d1; candd[o + 2] = d2;
  candi[o] = i0; candi[o + 1] = i1; candi[o + 2] = i2;
}

// Stage 2: block = pivotal point; thread t merges chunks 2t,2t+1 (coalesced reads).
__global__ void knnA_merge(const float* __restrict__ candd, const int* __restrict__ candi,
                           float* __restrict__ wA, int* __restrict__ idxA) {
  const int p = blockIdx.x;
  const int t = threadIdx.x;
  __shared__ float sd[PP * 3];
  __shared__ int si[PP * 3];
  __shared__ float sd2[32 * 3];
  __shared__ int si2[32 * 3];

  float d0 = INF_F, d1 = INF_F, d2 = INF_F;
  int i0 = 0, i1 = 0, i2 = 0;
#pragma unroll
  for (int cc = 0; cc < 2; ++cc) {
    int o = (p * CHUNKS + 2 * t + cc) * 3;
#pragma unroll
    for (int k = 0; k < 3; ++k) ins3(candd[o + k], candi[o + k], d0, d1, d2, i0, i1, i2);
  }
  sd[t * 3] = d0; sd[t * 3 + 1] = d1; sd[t * 3 + 2] = d2;
  si[t * 3] = i0; si[t * 3 + 1] = i1; si[t * 3 + 2] = i2;
  __syncthreads();
  if (t < 32) {
    d0 = d1 = d2 = INF_F; i0 = i1 = i2 = 0;
    for (int j = t * 8; j < t * 8 + 8; ++j)
      for (int k = 0; k < 3; ++k) ins3(sd[j * 3 + k], si[j * 3 + k], d0, d1, d2, i0, i1, i2);
    sd2[t * 3] = d0; sd2[t * 3 + 1] = d1; sd2[t * 3 + 2] = d2;
    si2[t * 3] = i0; si2[t * 3 + 1] = i1; si2[t * 3 + 2] = i2;
  }
  __syncthreads();
  if (t == 0) {
    d0 = d1 = d2 = INF_F; i0 = i1 = i2 = 0;
    for (int j = 0; j < 32; ++j)
      for (int k = 0; k < 3; ++k) ins3(sd2[j * 3 + k], si2[j * 3 + k], d0, d1, d2, i0, i1, i2);
    wA[p * 3 + 0] = 1.0f / fmaxf(d0, 1e-16f); idxA[p * 3 + 0] = i0;
    wA[p * 3 + 1] = 1.0f / fmaxf(d1, 1e-16f); idxA[p * 3 + 1] = i1;
    wA[p * 3 + 2] = 1.0f / fmaxf(d2, 1e-16f); idxA[p * 3 + 2] = i2;
  }
}

// ---------- Gather + LayerNorm + weighted interp -> y[B,256,3] ----------
__global__ void gather_ln(const float* __restrict__ node, const float* __restrict__ wA,
                          const int* __restrict__ idxA, const float* __restrict__ gamma,
                          const float* __restrict__ beta, float* __restrict__ y) {
  const int b = blockIdx.x >> 2;
  const int p = ((blockIdx.x & 3) << 6) + threadIdx.x;
  const float g0 = gamma[0], g1 = gamma[1], g2 = gamma[2];
  const float be0 = beta[0], be1 = beta[1], be2 = beta[2];
  float num0 = 0.f, num1 = 0.f, num2 = 0.f, den = 0.f;
#pragma unroll
  for (int k = 0; k < 3; ++k) {
    int idx = idxA[p * 3 + k];
    float w = wA[p * 3 + k];
    const float* r = node + ((size_t)b * NM + idx) * 3;
    float a0 = r[0], a1 = r[1], a2 = r[2];
    float mu = (a0 + a1 + a2) * (1.0f / 3.0f);
    float e0 = a0 - mu, e1 = a1 - mu, e2 = a2 - mu;
    float var = (e0 * e0 + e1 * e1 + e2 * e2) * (1.0f / 3.0f);
    float sc = 1.0f / sqrtf(var + 1e-5f);
    float v0 = e0 * sc * g0 + be0, v1 = e1 * sc * g1 + be1, v2 = e2 * sc * g2 + be2;
    num0 += v0 * w; num1 += v1 * w; num2 += v2 * w; den += w;
  }
  int o = (b * PP + p) * 3;
  y[o] = num0 / den; y[o + 1] = num1 / den; y[o + 2] = num2 / den;
}

// ---------- q/Q/K projection; output head-major Qh/Kh [b][h][q][16] ----------
// __launch_bounds__(128, 2): VGPR budget 256/wave so wreg[64] stays in
// registers (R3 post-mortem: default 64-VGPR cap spilled it to scratch ->
// 115 MB of scratch traffic, VALUBusy ~0, 51-92 us).
__global__ __launch_bounds__(128, 2)
void qqk_kernel(const float* __restrict__ y, const float* __restrict__ piv,
                const float* __restrict__ Wf, const float* __restrict__ bf,
                const float* __restrict__ Wp, const float* __restrict__ bp,
                const float* __restrict__ ipw, const float* __restrict__ ipb,
                float* __restrict__ Qh, float* __restrict__ Kh) {
  const int b = blockIdx.x >> 5;
  const int ptile = (blockIdx.x & 31) * 8;
  const int t = threadIdx.x;
  const int e = t & 63;
  const int half = t >> 6;  // 0 -> Q, 1 -> K
  __shared__ float qs[8][64];

  {
    float wf0 = Wf[e * 3], wf1 = Wf[e * 3 + 1], wf2 = Wf[e * 3 + 2];
    float wp0 = Wp[e * 2], wp1 = Wp[e * 2 + 1];
    float cst = bf[e] + bp[e];
    for (int r = half; r < 8; r += 2) {
      int p = ptile + r;
      const float* yr = y + (b * PP + p) * 3;
      float pe = piv[2 * p] * wp0 + piv[2 * p + 1] * wp1;
      qs[r][e] = yr[0] * wf0 + yr[1] * wf1 + yr[2] * wf2 + cst + pe;
    }
  }
  __syncthreads();

  const int row = half * 64 + e;
  float wreg[64];
  const float4* W4 = (const float4*)(ipw + row * 64);
#pragma unroll
  for (int j = 0; j < 16; ++j) {
    float4 v = W4[j];
    wreg[4 * j] = v.x; wreg[4 * j + 1] = v.y; wreg[4 * j + 2] = v.z; wreg[4 * j + 3] = v.w;
  }
  float bias = ipb[row];
  float* dst = half ? Kh : Qh;
  const int h = e >> 4, d = e & 15;
  for (int r = 0; r < 8; ++r) {
    float acc = bias;
#pragma unroll
    for (int j = 0; j < 64; ++j) acc += qs[r][j] * wreg[j];
    int p = ptile + r;
    dst[(((b * 4 + h) * PP) + p) * 16 + d] = acc;
  }
}

// ---------- attention: block = (b, h, q-half); thread = q-row; online softmax ----------
__global__ void attn_kernel(const float* __restrict__ Qh, const float* __restrict__ Kh,
                            const float* __restrict__ y, float* __restrict__ y2) {
  const int b = blockIdx.x >> 3;
  const int h = (blockIdx.x >> 1) & 3;
  const int qh = blockIdx.x & 1;
  const int t = threadIdx.x;          // 128 threads
  const int q = qh * 128 + t;

  __shared__ float Ks[PP * 16];       // 16 KB, head h's K
  __shared__ float ys[PP * 3];        // 3 KB

  {
    const float4* src = (const float4*)(Kh + (size_t)(b * 4 + h) * PP * 16);
    float4* dst = (float4*)Ks;
#pragma unroll
    for (int j = 0; j < 8; ++j) dst[j * 128 + t] = src[j * 128 + t];
    const float* ysrc = y + b * PP * 3;
#pragma unroll
    for (int j = 0; j < 6; ++j) ys[j * 128 + t] = ysrc[j * 128 + t];
  }
  __syncthreads();

  const float4* q4 = (const float4*)(Qh + ((size_t)((b * 4 + h) * PP) + q) * 16);
  float4 qa = q4[0], qb = q4[1], qc = q4[2], qd = q4[3];

  float m = -INF_F, l = 0.f, a0 = 0.f, a1 = 0.f, a2 = 0.f;
#pragma unroll 4
  for (int k = 0; k < PP; ++k) {
    const float4* kr = (const float4*)(Ks + k * 16);   // broadcast read
    float4 k0 = kr[0], k1 = kr[1], k2 = kr[2], k3 = kr[3];
    float dot = qa.x * k0.x + qa.y * k0.y + qa.z * k0.z + qa.w * k0.w
              + qb.x * k1.x + qb.y * k1.y + qb.z * k1.z + qb.w * k1.w
              + qc.x * k2.x + qc.y * k2.y + qc.z * k2.z + qc.w * k2.w
              + qd.x * k3.x + qd.y * k3.y + qd.z * k3.z + qd.w * k3.w;
    float s = dot * 0.25f;            // 1/sqrt(DH=16)
    float mn = fmaxf(m, s);
    float p = __expf(s - mn);
    float sc = __expf(m - mn);
    float y0 = ys[k * 3], y1 = ys[k * 3 + 1], yy2 = ys[k * 3 + 2];
    l = l * sc + p;
    a0 = a0 * sc + p * y0;
    a1 = a1 * sc + p * y1;
    a2 = a2 * sc + p * yy2;
    m = mn;
  }
  float inv = 0.25f / l;              // mean over 4 heads
  float* o = y2 + (b * PP + q) * 3;
  atomicAdd(o + 0, a0 * inv);
  atomicAdd(o + 1, a1 * inv);
  atomicAdd(o + 2, a2 * inv);
}

// ---------- KNN B + output: 4 insert chains per thread, nt stores ----------
__global__ void knnB_out(const float* __restrict__ mesh, const float* __restrict__ piv,
                         const float* __restrict__ y2, float* __restrict__ out) {
  const int m = blockIdx.x * blockDim.x + threadIdx.x;
  const float mx = mesh[2 * m], my = mesh[2 * m + 1];
  float D0[4], D1[4], D2[4];
  int I0[4], I1[4], I2[4];
#pragma unroll
  for (int j = 0; j < 4; ++j) { D0[j] = D1[j] = D2[j] = INF_F; I0[j] = I1[j] = I2[j] = 0; }
#pragma unroll 2
  for (int i = 0; i < PP / 4; ++i) {
#pragma unroll
    for (int j = 0; j < 4; ++j) {
      int idx = j * (PP / 4) + i;
      float px = piv[2 * idx], py = piv[2 * idx + 1];  // wave-uniform -> scalar loads
      ins3(dist2(mx, my, px, py), idx, D0[j], D1[j], D2[j], I0[j], I1[j], I2[j]);
    }
  }
  float d0 = D0[0], d1 = D1[0], d2 = D2[0];
  int i0 = I0[0], i1 = I1[0], i2 = I2[0];
#pragma unroll
  for (int j = 1; j < 4; ++j) {
    ins3(D0[j], I0[j], d0, d1, d2, i0, i1, i2);
    ins3(D1[j], I1[j], d0, d1, d2, i0, i1, i2);
    ins3(D2[j], I2[j], d0, d1, d2, i0, i1, i2);
  }
  float w0 = 1.0f / fmaxf(d0, 1e-16f);
  float w1 = 1.0f / fmaxf(d1, 1e-16f);
  float w2 = 1.0f / fmaxf(d2, 1e-16f);
  float inv = 1.0f / (w0 + w1 + w2);
  int o0 = i0 * 3, o1 = i1 * 3, o2 = i2 * 3;
#pragma unroll 4
  for (int b = 0; b < BB; ++b) {
    const float* yb = y2 + b * PP * 3;
    float n0 = (w0 * yb[o0] + w1 * yb[o1] + w2 * yb[o2]) * inv;
    float n1 = (w0 * yb[o0 + 1] + w1 * yb[o1 + 1] + w2 * yb[o2 + 1]) * inv;
    float n2 = (w0 * yb[o0 + 2] + w1 * yb[o1 + 2] + w2 * yb[o2 + 2]) * inv;
    float* op = out + ((size_t)b * NM + m) * 3;
    __builtin_nontemporal_store(n0, op + 0);
    __builtin_nontemporal_store(n1, op + 1);
    __builtin_nontemporal_store(n2, op + 2);
  }
}

extern "C" void kernel_launch(void* const* d_in, const int* in_sizes, int n_in,
                              void* d_out, int out_size, void* d_ws, size_t ws_size,
                              hipStream_t stream) {
  const float* node  = (const float*)d_in[0];
  const float* mesh  = (const float*)d_in[1];
  const float* piv   = (const float*)d_in[2];
  const float* gamma = (const float*)d_in[3];
  const float* beta  = (const float*)d_in[4];
  const float* Wf    = (const float*)d_in[5];
  const float* bf    = (const float*)d_in[6];
  const float* Wp    = (const float*)d_in[7];
  const float* bp    = (const float*)d_in[8];
  const float* ipw   = (const float*)d_in[9];
  const float* ipb   = (const float*)d_in[10];
  float* out = (float*)d_out;

  // workspace layout (floats)
  float* candd = (float*)d_ws;                     // PP*CHUNKS*3 (transposed [p][c])
  int*   candi = (int*)(candd + CHUNKS * PP * 3);  // PP*CHUNKS*3
  float* wA    = (float*)(candi + CHUNKS * PP * 3);// PP*3
  int*   idxA  = (int*)(wA + PP * 3);              // PP*3
  float* y     = (float*)(idxA + PP * 3);          // BB*PP*3
  float* Qh    = y + BB * PP * 3;                  // BB*4*PP*16
  float* Kh    = Qh + BB * PP * 64;                // BB*4*PP*16
  float* y2    = Kh + BB * PP * 64;                // BB*PP*3

  hipMemsetAsync(y2, 0, BB * PP * 3 * sizeof(float), stream);

  knnA_partial<<<CHUNKS, PP, 0, stream>>>(mesh, piv, candd, candi);
  knnA_merge<<<PP, 256, 0, stream>>>(candd, candi, wA, idxA);
  gather_ln<<<BB * 4, 64, 0, stream>>>(node, wA, idxA, gamma, beta, y);
  qqk_kernel<<<BB * 32, 128, 0, stream>>>(y, piv, Wf, bf, Wp, bp, ipw, ipb, Qh, Kh);
  attn_kernel<<<BB * 4 * 2, 128, 0, stream>>>(Qh, Kh, y, y2);
  knnB_out<<<NM / 256, 256, 0, stream>>>(mesh, piv, y2, out);
}

// Round 5
// 212.457 us; speedup vs baseline: 1.2935x; 1.0907x over previous
//
#include <hip/hip_runtime.h>
#include <math.h>

#define NM 131072
#define PP 256
#define BB 32

#define CHUNKS 512
#define CHUNK_SZ 256   // NM / CHUNKS

#define INF_F 3.0e38f
#define LDW 13         // padded LDS stride (13 coprime 32 -> conflict-free)

// Branchless sorted insert into (d0<=d1<=d2) top-3 list.
// Strict < : on exact ties the incumbent (earlier-scanned = lower index) wins,
// matching lax.top_k stable tie-break. Chains must scan ascending contiguous
// ranges and merge in range order to preserve this.
__device__ __forceinline__ void ins3(float d, int i,
    float& d0, float& d1, float& d2, int& i0, int& i1, int& i2) {
  bool l0 = d < d0, l1 = d < d1, l2 = d < d2;
  d2 = l1 ? d1 : (l2 ? d : d2);
  i2 = l1 ? i1 : (l2 ? i : i2);
  d1 = l0 ? d0 : (l1 ? d : d1);
  i1 = l0 ? i0 : (l1 ? i : i1);
  d0 = l0 ? d : d0;
  i0 = l0 ? i : i0;
}

// Exact-fp32 distance matching the reference's (a-b)^2 + (c-d)^2 (no fma contraction).
__device__ __forceinline__ float dist2(float ax, float ay, float bx, float by) {
  float dx = ax - bx, dy = ay - by;
  return __fadd_rn(__fmul_rn(dx, dx), __fmul_rn(dy, dy));
}

// ---------- KNN A stage 1: block = chunk, 1024 thr = 256 piv x 4 subs ----------
// R4 post-mortem: 2048 waves (2/SIMD) left VALUBusy at 36% regardless of ILP.
// 4-way thread split -> 8192 waves (32/CU) for latency hiding.
__global__ __launch_bounds__(1024)
void knnA_partial(const float* __restrict__ mesh, const float* __restrict__ piv,
                  float* __restrict__ candd, int* __restrict__ candi) {
  const int c = blockIdx.x;
  const int tid = threadIdx.x;
  const int p = tid & 255;
  const int sub = tid >> 8;          // 0..3, wave-uniform
  __shared__ float sdf[256 * LDW];
  __shared__ int   sif[256 * LDW];

  const float2 pv = ((const float2*)piv)[p];   // per-lane, coalesced
  float d0 = INF_F, d1 = INF_F, d2 = INF_F;
  int i0 = 0, i1 = 0, i2 = 0;
  const int base = c * CHUNK_SZ + sub * 64;
#pragma unroll 4
  for (int i = 0; i < 64; ++i) {
    float mx = mesh[2 * (base + i)];           // wave-uniform -> scalar load
    float my = mesh[2 * (base + i) + 1];
    ins3(dist2(pv.x, pv.y, mx, my), base + i, d0, d1, d2, i0, i1, i2);
  }
  sdf[p * LDW + sub * 3 + 0] = d0; sif[p * LDW + sub * 3 + 0] = i0;
  sdf[p * LDW + sub * 3 + 1] = d1; sif[p * LDW + sub * 3 + 1] = i1;
  sdf[p * LDW + sub * 3 + 2] = d2; sif[p * LDW + sub * 3 + 2] = i2;
  __syncthreads();

  if (tid < 256) {
    float e0 = sdf[tid * LDW + 0], e1 = sdf[tid * LDW + 1], e2 = sdf[tid * LDW + 2];
    int j0 = sif[tid * LDW + 0], j1 = sif[tid * LDW + 1], j2 = sif[tid * LDW + 2];
#pragma unroll
    for (int s = 1; s < 4; ++s)
#pragma unroll
      for (int k = 0; k < 3; ++k)
        ins3(sdf[tid * LDW + s * 3 + k], sif[tid * LDW + s * 3 + k], e0, e1, e2, j0, j1, j2);
    // transposed layout [p][c] so the merge kernel reads coalesced
    int o = (tid * CHUNKS + c) * 3;
    candd[o] = e0; candd[o + 1] = e1; candd[o + 2] = e2;
    candi[o] = j0; candi[o + 1] = j1; candi[o + 2] = j2;
  }
}

// Stage 2: block = pivotal point; thread t merges chunks 2t,2t+1 (coalesced reads).
__global__ void knnA_merge(const float* __restrict__ candd, const int* __restrict__ candi,
                           float* __restrict__ wA, int* __restrict__ idxA) {
  const int p = blockIdx.x;
  const int t = threadIdx.x;
  __shared__ float sd[PP * 3];
  __shared__ int si[PP * 3];
  __shared__ float sd2[32 * 3];
  __shared__ int si2[32 * 3];

  float d0 = INF_F, d1 = INF_F, d2 = INF_F;
  int i0 = 0, i1 = 0, i2 = 0;
#pragma unroll
  for (int cc = 0; cc < 2; ++cc) {
    int o = (p * CHUNKS + 2 * t + cc) * 3;
#pragma unroll
    for (int k = 0; k < 3; ++k) ins3(candd[o + k], candi[o + k], d0, d1, d2, i0, i1, i2);
  }
  sd[t * 3] = d0; sd[t * 3 + 1] = d1; sd[t * 3 + 2] = d2;
  si[t * 3] = i0; si[t * 3 + 1] = i1; si[t * 3 + 2] = i2;
  __syncthreads();
  if (t < 32) {
    d0 = d1 = d2 = INF_F; i0 = i1 = i2 = 0;
    for (int j = t * 8; j < t * 8 + 8; ++j)
      for (int k = 0; k < 3; ++k) ins3(sd[j * 3 + k], si[j * 3 + k], d0, d1, d2, i0, i1, i2);
    sd2[t * 3] = d0; sd2[t * 3 + 1] = d1; sd2[t * 3 + 2] = d2;
    si2[t * 3] = i0; si2[t * 3 + 1] = i1; si2[t * 3 + 2] = i2;
  }
  __syncthreads();
  if (t == 0) {
    d0 = d1 = d2 = INF_F; i0 = i1 = i2 = 0;
    for (int j = 0; j < 32; ++j)
      for (int k = 0; k < 3; ++k) ins3(sd2[j * 3 + k], si2[j * 3 + k], d0, d1, d2, i0, i1, i2);
    wA[p * 3 + 0] = 1.0f / fmaxf(d0, 1e-16f); idxA[p * 3 + 0] = i0;
    wA[p * 3 + 1] = 1.0f / fmaxf(d1, 1e-16f); idxA[p * 3 + 1] = i1;
    wA[p * 3 + 2] = 1.0f / fmaxf(d2, 1e-16f); idxA[p * 3 + 2] = i2;
  }
}

// ---------- Gather + LayerNorm + weighted interp -> y[B,256,3] ----------
__global__ void gather_ln(const float* __restrict__ node, const float* __restrict__ wA,
                          const int* __restrict__ idxA, const float* __restrict__ gamma,
                          const float* __restrict__ beta, float* __restrict__ y) {
  const int b = blockIdx.x >> 2;
  const int p = ((blockIdx.x & 3) << 6) + threadIdx.x;
  const float g0 = gamma[0], g1 = gamma[1], g2 = gamma[2];
  const float be0 = beta[0], be1 = beta[1], be2 = beta[2];
  float num0 = 0.f, num1 = 0.f, num2 = 0.f, den = 0.f;
#pragma unroll
  for (int k = 0; k < 3; ++k) {
    int idx = idxA[p * 3 + k];
    float w = wA[p * 3 + k];
    const float* r = node + ((size_t)b * NM + idx) * 3;
    float a0 = r[0], a1 = r[1], a2 = r[2];
    float mu = (a0 + a1 + a2) * (1.0f / 3.0f);
    float e0 = a0 - mu, e1 = a1 - mu, e2 = a2 - mu;
    float var = (e0 * e0 + e1 * e1 + e2 * e2) * (1.0f / 3.0f);
    float sc = 1.0f / sqrtf(var + 1e-5f);
    float v0 = e0 * sc * g0 + be0, v1 = e1 * sc * g1 + be1, v2 = e2 * sc * g2 + be2;
    num0 += v0 * w; num1 += v1 * w; num2 += v2 * w; den += w;
  }
  int o = (b * PP + p) * 3;
  y[o] = num0 / den; y[o + 1] = num1 / den; y[o + 2] = num2 / den;
}

// ---------- q/Q/K projection; output head-major Qh/Kh [b][h][q][16] ----------
// __launch_bounds__(128, 2): VGPR budget 256/wave so wreg[64] stays in
// registers (R3 post-mortem: default 64-VGPR cap spilled it to scratch).
__global__ __launch_bounds__(128, 2)
void qqk_kernel(const float* __restrict__ y, const float* __restrict__ piv,
                const float* __restrict__ Wf, const float* __restrict__ bf,
                const float* __restrict__ Wp, const float* __restrict__ bp,
                const float* __restrict__ ipw, const float* __restrict__ ipb,
                float* __restrict__ Qh, float* __restrict__ Kh) {
  const int b = blockIdx.x >> 5;
  const int ptile = (blockIdx.x & 31) * 8;
  const int t = threadIdx.x;
  const int e = t & 63;
  const int half = t >> 6;  // 0 -> Q, 1 -> K
  __shared__ float qs[8][64];

  {
    float wf0 = Wf[e * 3], wf1 = Wf[e * 3 + 1], wf2 = Wf[e * 3 + 2];
    float wp0 = Wp[e * 2], wp1 = Wp[e * 2 + 1];
    float cst = bf[e] + bp[e];
    for (int r = half; r < 8; r += 2) {
      int p = ptile + r;
      const float* yr = y + (b * PP + p) * 3;
      float pe = piv[2 * p] * wp0 + piv[2 * p + 1] * wp1;
      qs[r][e] = yr[0] * wf0 + yr[1] * wf1 + yr[2] * wf2 + cst + pe;
    }
  }
  __syncthreads();

  const int row = half * 64 + e;
  float wreg[64];
  const float4* W4 = (const float4*)(ipw + row * 64);
#pragma unroll
  for (int j = 0; j < 16; ++j) {
    float4 v = W4[j];
    wreg[4 * j] = v.x; wreg[4 * j + 1] = v.y; wreg[4 * j + 2] = v.z; wreg[4 * j + 3] = v.w;
  }
  float bias = ipb[row];
  float* dst = half ? Kh : Qh;
  const int h = e >> 4, d = e & 15;
  for (int r = 0; r < 8; ++r) {
    float acc = bias;
#pragma unroll
    for (int j = 0; j < 64; ++j) acc += qs[r][j] * wreg[j];
    int p = ptile + r;
    dst[(((b * 4 + h) * PP) + p) * 16 + d] = acc;
  }
}

// ---------- attention: block = (b, h, q-half); thread = q-row; online softmax ----------
__global__ void attn_kernel(const float* __restrict__ Qh, const float* __restrict__ Kh,
                            const float* __restrict__ y, float* __restrict__ y2) {
  const int b = blockIdx.x >> 3;
  const int h = (blockIdx.x >> 1) & 3;
  const int qh = blockIdx.x & 1;
  const int t = threadIdx.x;          // 128 threads
  const int q = qh * 128 + t;

  __shared__ float Ks[PP * 16];       // 16 KB, head h's K
  __shared__ float ys[PP * 3];        // 3 KB

  {
    const float4* src = (const float4*)(Kh + (size_t)(b * 4 + h) * PP * 16);
    float4* dst = (float4*)Ks;
#pragma unroll
    for (int j = 0; j < 8; ++j) dst[j * 128 + t] = src[j * 128 + t];
    const float* ysrc = y + b * PP * 3;
#pragma unroll
    for (int j = 0; j < 6; ++j) ys[j * 128 + t] = ysrc[j * 128 + t];
  }
  __syncthreads();

  const float4* q4 = (const float4*)(Qh + ((size_t)((b * 4 + h) * PP) + q) * 16);
  float4 qa = q4[0], qb = q4[1], qc = q4[2], qd = q4[3];

  float m = -INF_F, l = 0.f, a0 = 0.f, a1 = 0.f, a2 = 0.f;
#pragma unroll 4
  for (int k = 0; k < PP; ++k) {
    const float4* kr = (const float4*)(Ks + k * 16);   // broadcast read
    float4 k0 = kr[0], k1 = kr[1], k2 = kr[2], k3 = kr[3];
    float dot = qa.x * k0.x + qa.y * k0.y + qa.z * k0.z + qa.w * k0.w
              + qb.x * k1.x + qb.y * k1.y + qb.z * k1.z + qb.w * k1.w
              + qc.x * k2.x + qc.y * k2.y + qc.z * k2.z + qc.w * k2.w
              + qd.x * k3.x + qd.y * k3.y + qd.z * k3.z + qd.w * k3.w;
    float s = dot * 0.25f;            // 1/sqrt(DH=16)
    float mn = fmaxf(m, s);
    float p = __expf(s - mn);
    float sc = __expf(m - mn);
    float y0 = ys[k * 3], y1 = ys[k * 3 + 1], yy2 = ys[k * 3 + 2];
    l = l * sc + p;
    a0 = a0 * sc + p * y0;
    a1 = a1 * sc + p * y1;
    a2 = a2 * sc + p * yy2;
    m = mn;
  }
  float inv = 0.25f / l;              // mean over 4 heads
  float* o = y2 + (b * PP + q) * 3;
  atomicAdd(o + 0, a0 * inv);
  atomicAdd(o + 1, a1 * inv);
  atomicAdd(o + 2, a2 * inv);
}

// ---------- KNN B + output: block = 64 mesh pts x 4 subs; 8192 waves ----------
// Phase 1: thread (ml, sub) scans piv[sub*64 .. +64). Phase 2: sub becomes
// batch-group (8 batches each); stores are wave-uniform in b, lane-contiguous.
__global__ __launch_bounds__(256)
void knnB_out(const float* __restrict__ mesh, const float* __restrict__ piv,
              const float* __restrict__ y2, float* __restrict__ out) {
  const int tid = threadIdx.x;
  const int ml = tid & 63;
  const int sub = tid >> 6;          // wave-uniform
  const int m = blockIdx.x * 64 + ml;
  __shared__ float sdf[64 * LDW];
  __shared__ int   sif[64 * LDW];

  const float2 mv = ((const float2*)mesh)[m];  // per-lane, coalesced
  float d0 = INF_F, d1 = INF_F, d2 = INF_F;
  int i0 = 0, i1 = 0, i2 = 0;
  const int base = sub * 64;
#pragma unroll 4
  for (int i = 0; i < 64; ++i) {
    int idx = base + i;
    float px = piv[2 * idx], py = piv[2 * idx + 1];  // wave-uniform -> scalar
    ins3(dist2(mv.x, mv.y, px, py), idx, d0, d1, d2, i0, i1, i2);
  }
  sdf[ml * LDW + sub * 3 + 0] = d0; sif[ml * LDW + sub * 3 + 0] = i0;
  sdf[ml * LDW + sub * 3 + 1] = d1; sif[ml * LDW + sub * 3 + 1] = i1;
  sdf[ml * LDW + sub * 3 + 2] = d2; sif[ml * LDW + sub * 3 + 2] = i2;
  __syncthreads();

  // all 4 sub-threads duplicate the merge for their ml (cheap, conflict-free)
  float e0 = sdf[ml * LDW + 0], e1 = sdf[ml * LDW + 1], e2 = sdf[ml * LDW + 2];
  int j0 = sif[ml * LDW + 0], j1 = sif[ml * LDW + 1], j2 = sif[ml * LDW + 2];
#pragma unroll
  for (int s = 1; s < 4; ++s)
#pragma unroll
    for (int k = 0; k < 3; ++k)
      ins3(sdf[ml * LDW + s * 3 + k], sif[ml * LDW + s * 3 + k], e0, e1, e2, j0, j1, j2);

  float w0 = 1.0f / fmaxf(e0, 1e-16f);
  float w1 = 1.0f / fmaxf(e1, 1e-16f);
  float w2 = 1.0f / fmaxf(e2, 1e-16f);
  float inv = 1.0f / (w0 + w1 + w2);
  const int o0 = j0 * 3, o1 = j1 * 3, o2 = j2 * 3;

#pragma unroll 2
  for (int bi = 0; bi < 8; ++bi) {
    const int b = sub * 8 + bi;                       // wave-uniform
    const float* yb = y2 + b * PP * 3;
    float3 r0 = *(const float3*)(yb + o0);
    float3 r1 = *(const float3*)(yb + o1);
    float3 r2 = *(const float3*)(yb + o2);
    float3 res;
    res.x = (w0 * r0.x + w1 * r1.x + w2 * r2.x) * inv;
    res.y = (w0 * r0.y + w1 * r1.y + w2 * r2.y) * inv;
    res.z = (w0 * r0.z + w1 * r1.z + w2 * r2.z) * inv;
    *(float3*)(out + ((size_t)b * NM + m) * 3) = res; // lane-contiguous 12 B
  }
}

extern "C" void kernel_launch(void* const* d_in, const int* in_sizes, int n_in,
                              void* d_out, int out_size, void* d_ws, size_t ws_size,
                              hipStream_t stream) {
  const float* node  = (const float*)d_in[0];
  const float* mesh  = (const float*)d_in[1];
  const float* piv   = (const float*)d_in[2];
  const float* gamma = (const float*)d_in[3];
  const float* beta  = (const float*)d_in[4];
  const float* Wf    = (const float*)d_in[5];
  const float* bf    = (const float*)d_in[6];
  const float* Wp    = (const float*)d_in[7];
  const float* bp    = (const float*)d_in[8];
  const float* ipw   = (const float*)d_in[9];
  const float* ipb   = (const float*)d_in[10];
  float* out = (float*)d_out;

  // workspace layout (floats)
  float* candd = (float*)d_ws;                     // PP*CHUNKS*3 (transposed [p][c])
  int*   candi = (int*)(candd + CHUNKS * PP * 3);  // PP*CHUNKS*3
  float* wA    = (float*)(candi + CHUNKS * PP * 3);// PP*3
  int*   idxA  = (int*)(wA + PP * 3);              // PP*3
  float* y     = (float*)(idxA + PP * 3);          // BB*PP*3
  float* Qh    = y + BB * PP * 3;                  // BB*4*PP*16
  float* Kh    = Qh + BB * PP * 64;                // BB*4*PP*16
  float* y2    = Kh + BB * PP * 64;                // BB*PP*3

  hipMemsetAsync(y2, 0, BB * PP * 3 * sizeof(float), stream);

  knnA_partial<<<CHUNKS, 1024, 0, stream>>>(mesh, piv, candd, candi);
  knnA_merge<<<PP, 256, 0, stream>>>(candd, candi, wA, idxA);
  gather_ln<<<BB * 4, 64, 0, stream>>>(node, wA, idxA, gamma, beta, y);
  qqk_kernel<<<BB * 32, 128, 0, stream>>>(y, piv, Wf, bf, Wp, bp, ipw, ipb, Qh, Kh);
  attn_kernel<<<BB * 4 * 2, 128, 0, stream>>>(Qh, Kh, y, y2);
  knnB_out<<<NM / 64, 256, 0, stream>>>(mesh, piv, y2, out);
}